// Round 14
// baseline (4683.962 us; speedup 1.0000x reference)
//
#include <hip/hip_runtime.h>
#include <math.h>

#define NB 4
#define NPT 1024
#define KNN 20
#define NROW (NB*NPT)

// ---------------- K1: transpose input (B,3,N) -> (B,N,3) ----------------
__global__ __launch_bounds__(256) void k_transpose_in(const float* __restrict__ x,
                                                      float* __restrict__ X1) {
    int t = blockIdx.x*256 + threadIdx.x;            // over B*N*3
    if (t >= NB*NPT*3) return;
    int d = t % 3; int n = (t/3) % NPT; int b = t/(3*NPT);
    X1[t] = x[(b*3 + d)*NPT + n];
}

// ---------------- K2: per-row sum of squares (fp64) ----------------
__global__ __launch_bounds__(256) void k_row_sumsq(const float* __restrict__ X, int S, int F,
                                                   double* __restrict__ xx) {
    int lane = threadIdx.x & 63;
    int row  = blockIdx.x*4 + (threadIdx.x >> 6);
    const float* p = X + (size_t)row * S;
    double s = 0.0;
    for (int f = lane; f < F; f += 64) { double v = (double)p[f]; s += v*v; }
    for (int off = 32; off; off >>= 1) s += __shfl_down(s, off);
    if (lane == 0) xx[row] = s;
}

// ---------------- K3: tiled distance, fp32 LDS + fp64 accumulate ----------------
__global__ __launch_bounds__(256) void k_dist(const float* __restrict__ X, int S, int F,
                                              const double* __restrict__ xx,
                                              double* __restrict__ dist) {
    extern __shared__ float ds[];
    int b = blockIdx.z, n0 = blockIdx.y*16, m0 = blockIdx.x*16;
    const int CH = 384;
    int Fp = (F < CH ? F : CH) + 1;
    float* Xn = ds;
    float* Xm = ds + 16*Fp;
    double acc = 0.0;
    int mi = threadIdx.x & 15, ni = threadIdx.x >> 4;
    for (int f0 = 0; f0 < F; f0 += CH) {
        int fc = F - f0; if (fc > CH) fc = CH;
        __syncthreads();
        for (int t = threadIdx.x; t < 16*fc; t += 256) {
            int r = t / fc, c = t - r*fc;
            Xn[r*Fp + c] = X[((size_t)(b*NPT + n0 + r))*S + f0 + c];
            Xm[r*Fp + c] = X[((size_t)(b*NPT + m0 + r))*S + f0 + c];
        }
        __syncthreads();
        const float* an = Xn + ni*Fp;
        const float* am = Xm + mi*Fp;
        for (int f = 0; f < fc; ++f)
            acc = fma((double)an[f], (double)am[f], acc);
    }
    dist[((size_t)(b*NPT + n0 + ni))*NPT + (m0 + mi)] = 2.0*acc - xx[b*NPT + m0 + mi];
}

// ---------------- K4: top-20, register-resident + shuffle reduce ----------------
__global__ __launch_bounds__(256) void k_topk(const double* __restrict__ dist,
                                              int* __restrict__ idxo) {
    __shared__ double wv[4];
    __shared__ int    wi[4];
    int row = blockIdx.x;                            // b*N+n
    const double* dr = dist + (size_t)row * NPT;
    double v[4];
    #pragma unroll
    for (int q = 0; q < 4; ++q) v[q] = dr[threadIdx.x + 256*q];
    for (int k = 0; k < KNN; ++k) {
        double bv = v[0]; int bq = 0;
        #pragma unroll
        for (int q = 1; q < 4; ++q)
            if (v[q] > bv) { bv = v[q]; bq = q; }    // strict >: lower q (lower idx) wins ties
        int bi = threadIdx.x + 256*bq;
        #pragma unroll
        for (int off = 32; off; off >>= 1) {
            double ov = __shfl_xor(bv, off);
            int    oi = __shfl_xor(bi, off);
            if (ov > bv || (ov == bv && oi < bi)) { bv = ov; bi = oi; }
        }
        int w = threadIdx.x >> 6;
        if ((threadIdx.x & 63) == 0) { wv[w] = bv; wi[w] = bi; }
        __syncthreads();
        double gbv = wv[0]; int gbi = wi[0];
        #pragma unroll
        for (int w2 = 1; w2 < 4; ++w2)
            if (wv[w2] > gbv || (wv[w2] == gbv && wi[w2] < gbi)) { gbv = wv[w2]; gbi = wi[w2]; }
        if (threadIdx.x == 0) idxo[row*KNN + k] = gbi;
        if ((gbi & 255) == threadIdx.x) v[gbi >> 8] = -1.0e300;
        __syncthreads();
    }
}

// ---------------- K5a: Y/Z precompute, layer-1 only (C=1, W is L1-resident) ----------------
template<int CO, int C>
__global__ __launch_bounds__(256) void k_yz(const float* __restrict__ X, int S,
                                            const float* __restrict__ Wf,
                                            const float* __restrict__ Wd,
                                            float* __restrict__ Yf, float* __restrict__ Zf,
                                            float* __restrict__ Yd, float* __restrict__ Zd) {
    extern __shared__ float xl[];                    // [4][C*3]
    constexpr int REP = 256/CO;
    constexpr int PPG = 4/REP;                       // points per thread
    int p0 = blockIdx.x * 4;
    for (int t = threadIdx.x; t < 4*C*3; t += 256) {
        int pt = t / (C*3); int r = t - pt*(C*3);
        xl[t] = X[((size_t)(p0 + pt))*S + r];
    }
    __syncthreads();
    int co  = threadIdx.x % CO;
    int sub = threadIdx.x / CO;
    float yf[PPG][3] = {}, zf[PPG][3] = {}, yd[PPG][3] = {}, zd[PPG][3] = {};
    const float* wfr = Wf + (size_t)co*2*C;
    const float* wdr = Wd + (size_t)co*2*C;
    for (int i = 0; i < C; ++i) {
        float wfa = wfr[i], wfb = wfr[C+i];
        float wda = wdr[i], wdb = wdr[C+i];
        float wfz = wfb - wfa, wdz = wdb - wda;
        #pragma unroll
        for (int q = 0; q < PPG; ++q) {
            int pt = sub*PPG + q;
            const float* xv = xl + pt*(C*3) + i*3;
            #pragma unroll
            for (int d3 = 0; d3 < 3; ++d3) {
                float xe = xv[d3];
                yf[q][d3] = fmaf(wfa, xe, yf[q][d3]);
                zf[q][d3] = fmaf(wfz, xe, zf[q][d3]);
                yd[q][d3] = fmaf(wda, xe, yd[q][d3]);
                zd[q][d3] = fmaf(wdz, xe, zd[q][d3]);
            }
        }
    }
    #pragma unroll
    for (int q = 0; q < PPG; ++q) {
        int pt = sub*PPG + q;
        size_t o = ((size_t)(p0+pt)*CO + co)*3;
        #pragma unroll
        for (int d3 = 0; d3 < 3; ++d3) {
            Yf[o+d3] = yf[q][d3]; Zf[o+d3] = zf[q][d3];
            Yd[o+d3] = yd[q][d3]; Zd[o+d3] = zd[q][d3];
        }
    }
}

// ---------------- K5b: Y/Z precompute, GEMM-style LDS tiling (layers 2-4) ----------------
template<int CO, int C>
__global__ __launch_bounds__(256) void k_yz2(const float* __restrict__ X, int S,
                                             const float* __restrict__ Wf,
                                             const float* __restrict__ Wd,
                                             float* __restrict__ Yf, float* __restrict__ Zf,
                                             float* __restrict__ Yd, float* __restrict__ Zd) {
    __shared__ float Waf[32][33], Wbf[32][33], Wad[32][33], Wbd[32][33];
    __shared__ float Xs[32][97];                     // 32 pt x 96 (=32i*3) +1 pad
    int co0 = blockIdx.x * 32;
    int p0  = blockIdx.y * 32;
    int tid = threadIdx.x;
    int tco = tid & 15;                              // thread owns co0+tco, co0+tco+16
    int tpt = tid >> 4;                              // thread owns 2 pts
    float yf[2][2][3] = {}, zf[2][2][3] = {}, yd[2][2][3] = {}, zd[2][2][3] = {};
    for (int i0 = 0; i0 < C; i0 += 32) {
        __syncthreads();
        for (int t = tid; t < 1024; t += 256) {
            int c = t >> 5, i = t & 31;
            const float* wfr = Wf + (size_t)(co0 + c)*2*C + i0 + i;
            const float* wdr = Wd + (size_t)(co0 + c)*2*C + i0 + i;
            Waf[c][i] = wfr[0];
            Wbf[c][i] = wfr[C];
            Wad[c][i] = wdr[0];
            Wbd[c][i] = wdr[C];
        }
        for (int t = tid; t < 32*96; t += 256) {
            int p = t / 96, r = t - p*96;
            Xs[p][r] = X[(size_t)(p0 + p)*S + i0*3 + r];
        }
        __syncthreads();
        for (int k = 0; k < 32; ++k) {
            float waf[2], wzf[2], wad[2], wzd[2];
            #pragma unroll
            for (int j = 0; j < 2; ++j) {
                int c = tco + 16*j;
                waf[j] = Waf[c][k];
                wzf[j] = Wbf[c][k] - waf[j];
                wad[j] = Wad[c][k];
                wzd[j] = Wbd[c][k] - wad[j];
            }
            float xv[2][3];
            #pragma unroll
            for (int q = 0; q < 2; ++q)
                #pragma unroll
                for (int d = 0; d < 3; ++d)
                    xv[q][d] = Xs[tpt*2+q][k*3+d];
            #pragma unroll
            for (int j = 0; j < 2; ++j)
                #pragma unroll
                for (int q = 0; q < 2; ++q)
                    #pragma unroll
                    for (int d = 0; d < 3; ++d) {
                        float xe = xv[q][d];
                        yf[j][q][d] = fmaf(waf[j], xe, yf[j][q][d]);
                        zf[j][q][d] = fmaf(wzf[j], xe, zf[j][q][d]);
                        yd[j][q][d] = fmaf(wad[j], xe, yd[j][q][d]);
                        zd[j][q][d] = fmaf(wzd[j], xe, zd[j][q][d]);
                    }
        }
    }
    #pragma unroll
    for (int q = 0; q < 2; ++q) {
        int pt = p0 + tpt*2 + q;
        #pragma unroll
        for (int j = 0; j < 2; ++j) {
            int co = co0 + tco + 16*j;
            size_t o = ((size_t)pt*CO + co)*3;
            #pragma unroll
            for (int d = 0; d < 3; ++d) {
                Yf[o+d] = yf[j][q][d];
                Zf[o+d] = zf[j][q][d];
                Yd[o+d] = yd[j][q][d];
                Zd[o+d] = zd[j][q][d];
            }
        }
    }
}

// ---------------- K6: pass A — 4 rows/block (grid 1024, 4 blocks/CU for latency hiding) ----------------
template<int CO>
__global__ __launch_bounds__(256) void k_passA(const float* __restrict__ Yf,
                                               const float* __restrict__ Zf,
                                               const int* __restrict__ idx,
                                               float* __restrict__ part) {
    constexpr int PNG = CO/64;                       // rows per sub-thread; (256/CO)*PNG = 4
    int co  = threadIdx.x % CO;
    int sub = threadIdx.x / CO;
    int p0  = blockIdx.x*4 + sub*PNG;
    float s = 0.f, q = 0.f;
    for (int pp = 0; pp < PNG; ++pp) {
        int row = p0 + pp;
        int b   = row >> 10;
        size_t zo = ((size_t)row*CO + co)*3;
        float z0 = Zf[zo], z1 = Zf[zo+1], z2 = Zf[zo+2];
        const int* ir = idx + row*KNN;
        #pragma unroll 4
        for (int k = 0; k < KNN; ++k) {
            int j = ir[k];
            size_t yo = ((size_t)((b<<10) + j)*CO + co)*3;
            float a0 = Yf[yo] + z0, a1 = Yf[yo+1] + z1, a2 = Yf[yo+2] + z2;
            float nn = sqrtf(a0*a0 + a1*a1 + a2*a2) + 1e-6f;
            s += nn; q += nn*nn;
        }
    }
    size_t o = ((size_t)blockIdx.x*256 + threadIdx.x)*2;
    part[o] = s; part[o+1] = q;
}

// ---------------- K7: stats finalize (fp64) ----------------
__global__ __launch_bounds__(64) void k_stats(const float* __restrict__ part, int nchunk, int CO,
                                              double cnt, float* __restrict__ mu,
                                              float* __restrict__ rstd) {
    int c = blockIdx.x*64 + threadIdx.x;
    if (c >= CO) return;
    double s = 0.0, q = 0.0;
    for (int ch = 0; ch < nchunk; ++ch) {
        size_t o = ((size_t)ch*CO + c)*2;
        s += (double)part[o]; q += (double)part[o+1];
    }
    double m = s/cnt;
    double v = q/cnt - m*m;
    mu[c]   = (float)m;
    rstd[c] = (float)(1.0/sqrt(v + 1e-5));
}

// ---------------- K8: pass B — 4 rows/block (grid 1024) ----------------
template<int CO>
__global__ __launch_bounds__(256) void k_passB(const float* __restrict__ Yf,
                                               const float* __restrict__ Zf,
                                               const float* __restrict__ Yd,
                                               const float* __restrict__ Zd,
                                               const int* __restrict__ idx,
                                               const float* __restrict__ mu,
                                               const float* __restrict__ rstd,
                                               const float* __restrict__ gam,
                                               const float* __restrict__ bet,
                                               float* __restrict__ XC, int choff) {
    constexpr int PNG = CO/64;                       // rows per sub-thread; (256/CO)*PNG = 4
    int co  = threadIdx.x % CO;
    int sub = threadIdx.x / CO;
    int p0  = blockIdx.x*4 + sub*PNG;
    float m = mu[co], rs = rstd[co], g = gam[co], bt = bet[co];
    for (int pp = 0; pp < PNG; ++pp) {
        int row = p0 + pp;
        int b   = row >> 10;
        size_t zo = ((size_t)row*CO + co)*3;
        float zf0 = Zf[zo], zf1 = Zf[zo+1], zf2 = Zf[zo+2];
        float zd0 = Zd[zo], zd1 = Zd[zo+1], zd2 = Zd[zo+2];
        const int* ir = idx + row*KNN;
        float a0 = 0.f, a1 = 0.f, a2 = 0.f;
        #pragma unroll 4
        for (int k = 0; k < KNN; ++k) {
            int j = ir[k];
            size_t yo = ((size_t)((b<<10) + j)*CO + co)*3;
            float pv0 = Yf[yo] + zf0, pv1 = Yf[yo+1] + zf1, pv2 = Yf[yo+2] + zf2;
            float d0  = Yd[yo] + zd0, d1  = Yd[yo+1] + zd1, d2  = Yd[yo+2] + zd2;
            float nn  = sqrtf(pv0*pv0 + pv1*pv1 + pv2*pv2) + 1e-6f;
            float nbn = (nn - m)*rs*g + bt;
            float sc  = nbn / nn;
            float q0 = sc*pv0, q1 = sc*pv1, q2 = sc*pv2;
            float dotv = sc*(pv0*d0 + pv1*d1 + pv2*d2);
            if (dotv < 0.f) {
                float dsq = d0*d0 + d1*d1 + d2*d2;
                float cc  = dotv/(dsq + 1e-6f);
                q0 -= cc*d0; q1 -= cc*d1; q2 -= cc*d2;
            }
            a0 += q0; a1 += q1; a2 += q2;
        }
        size_t oo = ((size_t)row*512 + choff + co)*3;
        XC[oo]   = a0*(1.f/KNN);
        XC[oo+1] = a1*(1.f/KNN);
        XC[oo+2] = a2*(1.f/KNN);
    }
}

// ---------------- K9: layer-5 GEMM, LDS-tiled, float4 W and X reads ----------------
#define G5_COT 64
#define G5_PTT 32
#define G5_KC  64
__global__ __launch_bounds__(256) void k_gemm5(const float* __restrict__ XC,
                                               const float* __restrict__ W5f,
                                               const float* __restrict__ W5d,
                                               float* __restrict__ P5,
                                               float* __restrict__ D5) {
    __shared__ __attribute__((aligned(16))) float Wfs[G5_KC][G5_COT+4];
    __shared__ __attribute__((aligned(16))) float Wds[G5_KC][G5_COT+4];
    __shared__ __attribute__((aligned(16))) float Xs[G5_PTT][G5_KC*3+4];
    int co0 = blockIdx.x * G5_COT;
    int p0  = blockIdx.y * G5_PTT;
    int tid = threadIdx.x;
    int tco = tid & 15;                              // 16 groups of 4 co
    int tpt = tid >> 4;                              // 16 groups of 2 pt
    float acc_f[4][2][3] = {};
    float acc_d[4][2][3] = {};
    for (int k0 = 0; k0 < 512; k0 += G5_KC) {
        __syncthreads();
        for (int t = tid; t < G5_COT*G5_KC; t += 256) {
            int c = t >> 6, k = t & 63;              // consecutive t -> consecutive k: coalesced
            Wfs[k][c] = W5f[(size_t)(co0 + c)*512 + k0 + k];
            Wds[k][c] = W5d[(size_t)(co0 + c)*512 + k0 + k];
        }
        for (int t = tid; t < G5_PTT*G5_KC*3; t += 256) {
            int p = t / (G5_KC*3), r = t - p*(G5_KC*3);
            Xs[p][r] = XC[(size_t)(p0 + p)*1536 + k0*3 + r];
        }
        __syncthreads();
        for (int kb = 0; kb < G5_KC; kb += 4) {
            float xq[2][12];
            #pragma unroll
            for (int q = 0; q < 2; ++q) {
                const float4* xp = reinterpret_cast<const float4*>(&Xs[tpt*2+q][kb*3]);
                float4 xa = xp[0], xb = xp[1], xc = xp[2];
                xq[q][0]=xa.x; xq[q][1]=xa.y; xq[q][2]=xa.z; xq[q][3]=xa.w;
                xq[q][4]=xb.x; xq[q][5]=xb.y; xq[q][6]=xb.z; xq[q][7]=xb.w;
                xq[q][8]=xc.x; xq[q][9]=xc.y; xq[q][10]=xc.z; xq[q][11]=xc.w;
            }
            #pragma unroll
            for (int kk = 0; kk < 4; ++kk) {
                int k = kb + kk;
                float4 wf4 = *reinterpret_cast<const float4*>(&Wfs[k][tco*4]);
                float4 wd4 = *reinterpret_cast<const float4*>(&Wds[k][tco*4]);
                float wfv[4] = {wf4.x, wf4.y, wf4.z, wf4.w};
                float wdv[4] = {wd4.x, wd4.y, wd4.z, wd4.w};
                #pragma unroll
                for (int j = 0; j < 4; ++j)
                    #pragma unroll
                    for (int q = 0; q < 2; ++q)
                        #pragma unroll
                        for (int d = 0; d < 3; ++d) {
                            float xe = xq[q][kk*3+d];
                            acc_f[j][q][d] = fmaf(wfv[j], xe, acc_f[j][q][d]);
                            acc_d[j][q][d] = fmaf(wdv[j], xe, acc_d[j][q][d]);
                        }
            }
        }
    }
    #pragma unroll
    for (int q = 0; q < 2; ++q) {
        int pt = p0 + tpt*2 + q;
        #pragma unroll
        for (int j = 0; j < 4; ++j) {
            int co = co0 + tco*4 + j;
            size_t o = ((size_t)pt*1024 + co)*3;
            P5[o]   = acc_f[j][q][0];
            P5[o+1] = acc_f[j][q][1];
            P5[o+2] = acc_f[j][q][2];
            D5[o]   = acc_d[j][q][0];
            D5[o+1] = acc_d[j][q][1];
            D5[o+2] = acc_d[j][q][2];
        }
    }
}

// ---------------- K10: layer-5 pass A ----------------
__global__ __launch_bounds__(256) void k_passA5(const float* __restrict__ P5,
                                                float* __restrict__ part) {
    int p0 = blockIdx.x*16;
    float s[4] = {}, q[4] = {};
    for (int pp = 0; pp < 16; ++pp) {
        size_t base = ((size_t)(p0+pp)*1024)*3;
        #pragma unroll
        for (int qq = 0; qq < 4; ++qq) {
            int co = qq*256 + threadIdx.x;
            size_t o = base + (size_t)co*3;
            float a = P5[o], b = P5[o+1], c = P5[o+2];
            float nn = sqrtf(a*a + b*b + c*c) + 1e-6f;
            s[qq] += nn; q[qq] += nn*nn;
        }
    }
    #pragma unroll
    for (int qq = 0; qq < 4; ++qq) {
        int co = qq*256 + threadIdx.x;
        size_t o = ((size_t)blockIdx.x*1024 + co)*2;
        part[o] = s[qq]; part[o+1] = q[qq];
    }
}

// ---------------- K11: layer-5 pass B (partial mean over n) ----------------
__global__ __launch_bounds__(256) void k_passB5(const float* __restrict__ P5,
                                                const float* __restrict__ D5,
                                                const float* __restrict__ mu,
                                                const float* __restrict__ rstd,
                                                const float* __restrict__ gam,
                                                const float* __restrict__ bet,
                                                float* __restrict__ part) {
    int p0 = blockIdx.x*16;
    float mm[4], rr[4], gg[4], bb[4];
    #pragma unroll
    for (int qq = 0; qq < 4; ++qq) {
        int co = qq*256 + threadIdx.x;
        mm[qq] = mu[co]; rr[qq] = rstd[co]; gg[qq] = gam[co]; bb[qq] = bet[co];
    }
    float acc[4][3] = {};
    for (int pp = 0; pp < 16; ++pp) {
        size_t base = ((size_t)(p0+pp)*1024)*3;
        #pragma unroll
        for (int qq = 0; qq < 4; ++qq) {
            int co = qq*256 + threadIdx.x;
            size_t o = base + (size_t)co*3;
            float a = P5[o], b = P5[o+1], c = P5[o+2];
            float d0 = D5[o], d1 = D5[o+1], d2 = D5[o+2];
            float nn = sqrtf(a*a + b*b + c*c) + 1e-6f;
            float sc = ((nn - mm[qq])*rr[qq]*gg[qq] + bb[qq])/nn;
            float q0 = sc*a, q1 = sc*b, q2 = sc*c;
            float dotv = sc*(a*d0 + b*d1 + c*d2);
            if (dotv < 0.f) {
                float dsq = d0*d0 + d1*d1 + d2*d2;
                float cc  = dotv/(dsq + 1e-6f);
                q0 -= cc*d0; q1 -= cc*d1; q2 -= cc*d2;
            }
            acc[qq][0] += q0; acc[qq][1] += q1; acc[qq][2] += q2;
        }
    }
    #pragma unroll
    for (int qq = 0; qq < 4; ++qq) {
        int co = qq*256 + threadIdx.x;
        size_t o = ((size_t)blockIdx.x*1024 + co)*3;
        part[o] = acc[qq][0]; part[o+1] = acc[qq][1]; part[o+2] = acc[qq][2];
    }
}

// ---------------- K12: final reduce over n-chunks -> d_out ----------------
__global__ __launch_bounds__(256) void k_outred(const float* __restrict__ part,
                                                float* __restrict__ out) {
    int t = blockIdx.x*256 + threadIdx.x;            // over B*1024*3
    if (t >= NB*1024*3) return;
    int d = t % 3; int co = (t/3) % 1024; int b = t/(3*1024);
    float s = 0.f;
    for (int ch = 0; ch < 64; ++ch)
        s += part[((size_t)(b*64 + ch)*1024 + co)*3 + d];
    out[t] = s * (1.f/1024.f);
}

// ---------------- host-side per-layer driver ----------------
template<int CO, int C>
static void run_layer(const float* Xin, int S, const float* Wf, const float* Wd,
                      const float* g, const float* bt, int choff,
                      double* XX, double* DIST, int* IDX,
                      float* Yf, float* Zf, float* Yd, float* Zd,
                      float* PA, float* MU, float* RS, float* XC, hipStream_t stream) {
    constexpr int F = 3*C;
    k_row_sumsq<<<dim3(NROW/4), dim3(256), 0, stream>>>(Xin, S, F, XX);
    size_t dsm = (size_t)2*16*((F < 384 ? F : 384) + 1)*4;   // fp32 staging
    k_dist<<<dim3(NPT/16, NPT/16, NB), dim3(256), dsm, stream>>>(Xin, S, F, XX, DIST);
    k_topk<<<dim3(NROW), dim3(256), 0, stream>>>(DIST, IDX);
    if constexpr (C >= 32) {
        k_yz2<CO, C><<<dim3(CO/32, NROW/32), dim3(256), 0, stream>>>(Xin, S, Wf, Wd, Yf, Zf, Yd, Zd);
    } else {
        k_yz<CO, C><<<dim3(NROW/4), dim3(256), (size_t)4*C*3*4, stream>>>(Xin, S, Wf, Wd, Yf, Zf, Yd, Zd);
    }
    k_passA<CO><<<dim3(NROW/4), dim3(256), 0, stream>>>(Yf, Zf, IDX, PA);
    k_stats<<<dim3((CO+63)/64), dim3(64), 0, stream>>>(PA, (NROW/4)*256/CO, CO, (double)((size_t)NROW*KNN), MU, RS);
    k_passB<CO><<<dim3(NROW/4), dim3(256), 0, stream>>>(Yf, Zf, Yd, Zd, IDX, MU, RS, g, bt, XC, choff);
}

extern "C" void kernel_launch(void* const* d_in, const int* in_sizes, int n_in,
                              void* d_out, int out_size, void* d_ws, size_t ws_size,
                              hipStream_t stream) {
    const float* x = (const float*)d_in[0];
    const float* Wf[5]; const float* Wd[5]; const float* G[5]; const float* Bt[5];
    for (int l = 0; l < 5; ++l) {
        Wf[l] = (const float*)d_in[1 + 4*l];
        Wd[l] = (const float*)d_in[2 + 4*l];
        G[l]  = (const float*)d_in[3 + 4*l];
        Bt[l] = (const float*)d_in[4 + 4*l];
    }
    float* ws = (float*)d_ws;
    // workspace layout (float slots)
    size_t oXC  = 0;                                 // 4*1024*512*3 = 6291456
    size_t oX1  = oXC  + (size_t)NROW*512*3;
    size_t oXX  = oX1  + (size_t)NROW*3;             // doubles: NROW*2 slots
    size_t oMU  = oXX  + (size_t)NROW*2;
    size_t oRS  = oMU  + 1024;
    size_t oPA  = oRS  + 1024;                       // 1024*256*2 = 524288
    size_t oPB5 = oPA  + (size_t)256*1024*2;
    size_t oIDX = oPB5 + (size_t)256*1024*3;
    size_t oBIG = oIDX + (size_t)NROW*KNN;
    float*  XC  = ws + oXC;
    float*  X1  = ws + oX1;
    double* XX  = (double*)(ws + oXX);
    float*  MU  = ws + oMU;
    float*  RS  = ws + oRS;
    float*  PA  = ws + oPA;
    float*  PB5 = ws + oPB5;
    int*    IDX = (int*)(ws + oIDX);
    // big region: (dist fp64 + Y/Z) overlapped with (P5 + D5)
    double* DIST = (double*)(ws + oBIG);             // 4194304 doubles = 8388608 slots
    float*  Yf = ws + oBIG + 8388608;
    float*  Zf = Yf + 3145728;
    float*  Yd = Zf + 3145728;
    float*  Zd = Yd + 3145728;
    float*  P5 = ws + oBIG;
    float*  D5 = P5 + (size_t)NROW*1024*3;

    (void)in_sizes; (void)n_in; (void)out_size; (void)ws_size;

    k_transpose_in<<<dim3(48), dim3(256), 0, stream>>>(x, X1);

    // layer 1: C=1 (F=3), CO=64, out channels [0,64)
    run_layer<64, 1>(X1, 3, Wf[0], Wd[0], G[0], Bt[0], 0,
                     XX, DIST, IDX, Yf, Zf, Yd, Zd, PA, MU, RS, XC, stream);
    // layer 2: input = XC[:, :, 0:64], CO=64, out [64,128)
    run_layer<64, 64>(XC + 0*3, 512*3, Wf[1], Wd[1], G[1], Bt[1], 64,
                      XX, DIST, IDX, Yf, Zf, Yd, Zd, PA, MU, RS, XC, stream);
    // layer 3: input = XC[:, :, 64:128], CO=128, out [128,256)
    run_layer<128, 64>(XC + 64*3, 512*3, Wf[2], Wd[2], G[2], Bt[2], 128,
                       XX, DIST, IDX, Yf, Zf, Yd, Zd, PA, MU, RS, XC, stream);
    // layer 4: input = XC[:, :, 128:256], CO=256, out [256,512)
    run_layer<256, 128>(XC + 128*3, 512*3, Wf[3], Wd[3], G[3], Bt[3], 256,
                        XX, DIST, IDX, Yf, Zf, Yd, Zd, PA, MU, RS, XC, stream);

    // layer 5 (tiled GEMM: grid 16 co-tiles x 128 pt-tiles)
    k_gemm5<<<dim3(16, 128), dim3(256), 0, stream>>>(XC, Wf[4], Wd[4], P5, D5);
    k_passA5<<<dim3(NROW/16), dim3(256), 0, stream>>>(P5, PA);
    k_stats<<<dim3(16), dim3(64), 0, stream>>>(PA, 256, 1024, (double)NROW, MU, RS);
    k_passB5<<<dim3(NROW/16), dim3(256), 0, stream>>>(P5, D5, MU, RS, G[4], Bt[4], PB5);
    k_outred<<<dim3(48), dim3(256), 0, stream>>>(PB5, (float*)d_out);
}

// Round 15
// 1808.114 us; speedup vs baseline: 2.5905x; 2.5905x over previous
//
#include <hip/hip_runtime.h>
#include <math.h>

#define NB 4
#define NPT 1024
#define KNN 20
#define NROW (NB*NPT)

// ---------------- K1: transpose input (B,3,N) -> (B,N,3) ----------------
__global__ __launch_bounds__(256) void k_transpose_in(const float* __restrict__ x,
                                                      float* __restrict__ X1) {
    int t = blockIdx.x*256 + threadIdx.x;            // over B*N*3
    if (t >= NB*NPT*3) return;
    int d = t % 3; int n = (t/3) % NPT; int b = t/(3*NPT);
    X1[t] = x[(b*3 + d)*NPT + n];
}

// ---------------- K2: per-row sum of squares (fp64) ----------------
__global__ __launch_bounds__(256) void k_row_sumsq(const float* __restrict__ X, int S, int F,
                                                   double* __restrict__ xx) {
    int lane = threadIdx.x & 63;
    int row  = blockIdx.x*4 + (threadIdx.x >> 6);
    const float* p = X + (size_t)row * S;
    double s = 0.0;
    for (int f = lane; f < F; f += 64) { double v = (double)p[f]; s += v*v; }
    for (int off = 32; off; off >>= 1) s += __shfl_down(s, off);
    if (lane == 0) xx[row] = s;
}

// ---------------- K3: tiled distance, fp32 LDS + fp64 accumulate ----------------
__global__ __launch_bounds__(256) void k_dist(const float* __restrict__ X, int S, int F,
                                              const double* __restrict__ xx,
                                              double* __restrict__ dist) {
    extern __shared__ float ds[];
    int b = blockIdx.z, n0 = blockIdx.y*16, m0 = blockIdx.x*16;
    const int CH = 384;
    int Fp = (F < CH ? F : CH) + 1;
    float* Xn = ds;
    float* Xm = ds + 16*Fp;
    double acc = 0.0;
    int mi = threadIdx.x & 15, ni = threadIdx.x >> 4;
    for (int f0 = 0; f0 < F; f0 += CH) {
        int fc = F - f0; if (fc > CH) fc = CH;
        __syncthreads();
        for (int t = threadIdx.x; t < 16*fc; t += 256) {
            int r = t / fc, c = t - r*fc;
            Xn[r*Fp + c] = X[((size_t)(b*NPT + n0 + r))*S + f0 + c];
            Xm[r*Fp + c] = X[((size_t)(b*NPT + m0 + r))*S + f0 + c];
        }
        __syncthreads();
        const float* an = Xn + ni*Fp;
        const float* am = Xm + mi*Fp;
        for (int f = 0; f < fc; ++f)
            acc = fma((double)an[f], (double)am[f], acc);
    }
    dist[((size_t)(b*NPT + n0 + ni))*NPT + (m0 + mi)] = 2.0*acc - xx[b*NPT + m0 + mi];
}

// ---------------- K4: top-20, register-resident + shuffle reduce ----------------
__global__ __launch_bounds__(256) void k_topk(const double* __restrict__ dist,
                                              int* __restrict__ idxo) {
    __shared__ double wv[4];
    __shared__ int    wi[4];
    int row = blockIdx.x;                            // b*N+n
    const double* dr = dist + (size_t)row * NPT;
    double v[4];
    #pragma unroll
    for (int q = 0; q < 4; ++q) v[q] = dr[threadIdx.x + 256*q];
    for (int k = 0; k < KNN; ++k) {
        double bv = v[0]; int bq = 0;
        #pragma unroll
        for (int q = 1; q < 4; ++q)
            if (v[q] > bv) { bv = v[q]; bq = q; }    // strict >: lower q (lower idx) wins ties
        int bi = threadIdx.x + 256*bq;
        #pragma unroll
        for (int off = 32; off; off >>= 1) {
            double ov = __shfl_xor(bv, off);
            int    oi = __shfl_xor(bi, off);
            if (ov > bv || (ov == bv && oi < bi)) { bv = ov; bi = oi; }
        }
        int w = threadIdx.x >> 6;
        if ((threadIdx.x & 63) == 0) { wv[w] = bv; wi[w] = bi; }
        __syncthreads();
        double gbv = wv[0]; int gbi = wi[0];
        #pragma unroll
        for (int w2 = 1; w2 < 4; ++w2)
            if (wv[w2] > gbv || (wv[w2] == gbv && wi[w2] < gbi)) { gbv = wv[w2]; gbi = wi[w2]; }
        if (threadIdx.x == 0) idxo[row*KNN + k] = gbi;
        if ((gbi & 255) == threadIdx.x) v[gbi >> 8] = -1.0e300;
        __syncthreads();
    }
}

// ---------------- K5a: Y/Z precompute, layer-1 only (C=1, W is L1-resident) ----------------
template<int CO, int C>
__global__ __launch_bounds__(256) void k_yz(const float* __restrict__ X, int S,
                                            const float* __restrict__ Wf,
                                            const float* __restrict__ Wd,
                                            float* __restrict__ Yf, float* __restrict__ Zf,
                                            float* __restrict__ Yd, float* __restrict__ Zd) {
    extern __shared__ float xl[];                    // [4][C*3]
    constexpr int REP = 256/CO;
    constexpr int PPG = 4/REP;                       // points per thread
    int p0 = blockIdx.x * 4;
    for (int t = threadIdx.x; t < 4*C*3; t += 256) {
        int pt = t / (C*3); int r = t - pt*(C*3);
        xl[t] = X[((size_t)(p0 + pt))*S + r];
    }
    __syncthreads();
    int co  = threadIdx.x % CO;
    int sub = threadIdx.x / CO;
    float yf[PPG][3] = {}, zf[PPG][3] = {}, yd[PPG][3] = {}, zd[PPG][3] = {};
    const float* wfr = Wf + (size_t)co*2*C;
    const float* wdr = Wd + (size_t)co*2*C;
    for (int i = 0; i < C; ++i) {
        float wfa = wfr[i], wfb = wfr[C+i];
        float wda = wdr[i], wdb = wdr[C+i];
        float wfz = wfb - wfa, wdz = wdb - wda;
        #pragma unroll
        for (int q = 0; q < PPG; ++q) {
            int pt = sub*PPG + q;
            const float* xv = xl + pt*(C*3) + i*3;
            #pragma unroll
            for (int d3 = 0; d3 < 3; ++d3) {
                float xe = xv[d3];
                yf[q][d3] = fmaf(wfa, xe, yf[q][d3]);
                zf[q][d3] = fmaf(wfz, xe, zf[q][d3]);
                yd[q][d3] = fmaf(wda, xe, yd[q][d3]);
                zd[q][d3] = fmaf(wdz, xe, zd[q][d3]);
            }
        }
    }
    #pragma unroll
    for (int q = 0; q < PPG; ++q) {
        int pt = sub*PPG + q;
        size_t o = ((size_t)(p0+pt)*CO + co)*3;
        #pragma unroll
        for (int d3 = 0; d3 < 3; ++d3) {
            Yf[o+d3] = yf[q][d3]; Zf[o+d3] = zf[q][d3];
            Yd[o+d3] = yd[q][d3]; Zd[o+d3] = zd[q][d3];
        }
    }
}

// ---------------- K5b: Y/Z precompute, GEMM-style LDS tiling (layers 2-4) ----------------
template<int CO, int C>
__global__ __launch_bounds__(256) void k_yz2(const float* __restrict__ X, int S,
                                             const float* __restrict__ Wf,
                                             const float* __restrict__ Wd,
                                             float* __restrict__ Yf, float* __restrict__ Zf,
                                             float* __restrict__ Yd, float* __restrict__ Zd) {
    __shared__ float Waf[32][33], Wbf[32][33], Wad[32][33], Wbd[32][33];
    __shared__ float Xs[32][97];                     // 32 pt x 96 (=32i*3) +1 pad
    int co0 = blockIdx.x * 32;
    int p0  = blockIdx.y * 32;
    int tid = threadIdx.x;
    int tco = tid & 15;                              // thread owns co0+tco, co0+tco+16
    int tpt = tid >> 4;                              // thread owns 2 pts
    float yf[2][2][3] = {}, zf[2][2][3] = {}, yd[2][2][3] = {}, zd[2][2][3] = {};
    for (int i0 = 0; i0 < C; i0 += 32) {
        __syncthreads();
        for (int t = tid; t < 1024; t += 256) {
            int c = t >> 5, i = t & 31;
            const float* wfr = Wf + (size_t)(co0 + c)*2*C + i0 + i;
            const float* wdr = Wd + (size_t)(co0 + c)*2*C + i0 + i;
            Waf[c][i] = wfr[0];
            Wbf[c][i] = wfr[C];
            Wad[c][i] = wdr[0];
            Wbd[c][i] = wdr[C];
        }
        for (int t = tid; t < 32*96; t += 256) {
            int p = t / 96, r = t - p*96;
            Xs[p][r] = X[(size_t)(p0 + p)*S + i0*3 + r];
        }
        __syncthreads();
        for (int k = 0; k < 32; ++k) {
            float waf[2], wzf[2], wad[2], wzd[2];
            #pragma unroll
            for (int j = 0; j < 2; ++j) {
                int c = tco + 16*j;
                waf[j] = Waf[c][k];
                wzf[j] = Wbf[c][k] - waf[j];
                wad[j] = Wad[c][k];
                wzd[j] = Wbd[c][k] - wad[j];
            }
            float xv[2][3];
            #pragma unroll
            for (int q = 0; q < 2; ++q)
                #pragma unroll
                for (int d = 0; d < 3; ++d)
                    xv[q][d] = Xs[tpt*2+q][k*3+d];
            #pragma unroll
            for (int j = 0; j < 2; ++j)
                #pragma unroll
                for (int q = 0; q < 2; ++q)
                    #pragma unroll
                    for (int d = 0; d < 3; ++d) {
                        float xe = xv[q][d];
                        yf[j][q][d] = fmaf(waf[j], xe, yf[j][q][d]);
                        zf[j][q][d] = fmaf(wzf[j], xe, zf[j][q][d]);
                        yd[j][q][d] = fmaf(wad[j], xe, yd[j][q][d]);
                        zd[j][q][d] = fmaf(wzd[j], xe, zd[j][q][d]);
                    }
        }
    }
    #pragma unroll
    for (int q = 0; q < 2; ++q) {
        int pt = p0 + tpt*2 + q;
        #pragma unroll
        for (int j = 0; j < 2; ++j) {
            int co = co0 + tco + 16*j;
            size_t o = ((size_t)pt*CO + co)*3;
            #pragma unroll
            for (int d = 0; d < 3; ++d) {
                Yf[o+d] = yf[j][q][d];
                Zf[o+d] = zf[j][q][d];
                Yd[o+d] = yd[j][q][d];
                Zd[o+d] = zd[j][q][d];
            }
        }
    }
}

// ---------------- K6: pass A — 4 rows/block (grid 1024) ----------------
template<int CO>
__global__ __launch_bounds__(256) void k_passA(const float* __restrict__ Yf,
                                               const float* __restrict__ Zf,
                                               const int* __restrict__ idx,
                                               float* __restrict__ part) {
    constexpr int PNG = CO/64;                       // rows per sub-thread; (256/CO)*PNG = 4
    int co  = threadIdx.x % CO;
    int sub = threadIdx.x / CO;
    int p0  = blockIdx.x*4 + sub*PNG;
    float s = 0.f, q = 0.f;
    for (int pp = 0; pp < PNG; ++pp) {
        int row = p0 + pp;
        int b   = row >> 10;
        size_t zo = ((size_t)row*CO + co)*3;
        float z0 = Zf[zo], z1 = Zf[zo+1], z2 = Zf[zo+2];
        const int* ir = idx + row*KNN;
        #pragma unroll 4
        for (int k = 0; k < KNN; ++k) {
            int j = ir[k];
            size_t yo = ((size_t)((b<<10) + j)*CO + co)*3;
            float a0 = Yf[yo] + z0, a1 = Yf[yo+1] + z1, a2 = Yf[yo+2] + z2;
            float nn = sqrtf(a0*a0 + a1*a1 + a2*a2) + 1e-6f;
            s += nn; q += nn*nn;
        }
    }
    size_t o = ((size_t)blockIdx.x*256 + threadIdx.x)*2;
    part[o] = s; part[o+1] = q;
}

// ---------------- K7: stats finalize, parallel (one block per channel, fp64 tree) ----------------
__global__ __launch_bounds__(256) void k_stats2(const float* __restrict__ part, int nchunk, int CO,
                                                double cnt, float* __restrict__ mu,
                                                float* __restrict__ rstd) {
    __shared__ double sv[4], qv[4];
    int c = blockIdx.x;                              // channel
    double s = 0.0, q = 0.0;
    for (int ch = threadIdx.x; ch < nchunk; ch += 256) {
        size_t o = ((size_t)ch*CO + c)*2;
        s += (double)part[o]; q += (double)part[o+1];
    }
    #pragma unroll
    for (int off = 32; off; off >>= 1) {
        s += __shfl_down(s, off);
        q += __shfl_down(q, off);
    }
    int w = threadIdx.x >> 6;
    if ((threadIdx.x & 63) == 0) { sv[w] = s; qv[w] = q; }
    __syncthreads();
    if (threadIdx.x == 0) {
        double S = sv[0] + sv[1] + sv[2] + sv[3];
        double Q = qv[0] + qv[1] + qv[2] + qv[3];
        double m = S/cnt;
        double v = Q/cnt - m*m;
        mu[c]   = (float)m;
        rstd[c] = (float)(1.0/sqrt(v + 1e-5));
    }
}

// ---------------- K8: pass B — 4 rows/block (grid 1024) ----------------
template<int CO>
__global__ __launch_bounds__(256) void k_passB(const float* __restrict__ Yf,
                                               const float* __restrict__ Zf,
                                               const float* __restrict__ Yd,
                                               const float* __restrict__ Zd,
                                               const int* __restrict__ idx,
                                               const float* __restrict__ mu,
                                               const float* __restrict__ rstd,
                                               const float* __restrict__ gam,
                                               const float* __restrict__ bet,
                                               float* __restrict__ XC, int choff) {
    constexpr int PNG = CO/64;                       // rows per sub-thread; (256/CO)*PNG = 4
    int co  = threadIdx.x % CO;
    int sub = threadIdx.x / CO;
    int p0  = blockIdx.x*4 + sub*PNG;
    float m = mu[co], rs = rstd[co], g = gam[co], bt = bet[co];
    for (int pp = 0; pp < PNG; ++pp) {
        int row = p0 + pp;
        int b   = row >> 10;
        size_t zo = ((size_t)row*CO + co)*3;
        float zf0 = Zf[zo], zf1 = Zf[zo+1], zf2 = Zf[zo+2];
        float zd0 = Zd[zo], zd1 = Zd[zo+1], zd2 = Zd[zo+2];
        const int* ir = idx + row*KNN;
        float a0 = 0.f, a1 = 0.f, a2 = 0.f;
        #pragma unroll 4
        for (int k = 0; k < KNN; ++k) {
            int j = ir[k];
            size_t yo = ((size_t)((b<<10) + j)*CO + co)*3;
            float pv0 = Yf[yo] + zf0, pv1 = Yf[yo+1] + zf1, pv2 = Yf[yo+2] + zf2;
            float d0  = Yd[yo] + zd0, d1  = Yd[yo+1] + zd1, d2  = Yd[yo+2] + zd2;
            float nn  = sqrtf(pv0*pv0 + pv1*pv1 + pv2*pv2) + 1e-6f;
            float nbn = (nn - m)*rs*g + bt;
            float sc  = nbn / nn;
            float q0 = sc*pv0, q1 = sc*pv1, q2 = sc*pv2;
            float dotv = sc*(pv0*d0 + pv1*d1 + pv2*d2);
            if (dotv < 0.f) {
                float dsq = d0*d0 + d1*d1 + d2*d2;
                float cc  = dotv/(dsq + 1e-6f);
                q0 -= cc*d0; q1 -= cc*d1; q2 -= cc*d2;
            }
            a0 += q0; a1 += q1; a2 += q2;
        }
        size_t oo = ((size_t)row*512 + choff + co)*3;
        XC[oo]   = a0*(1.f/KNN);
        XC[oo+1] = a1*(1.f/KNN);
        XC[oo+2] = a2*(1.f/KNN);
    }
}

// ---------------- K9: layer-5 GEMM, LDS-tiled, float4 W and X reads ----------------
#define G5_COT 64
#define G5_PTT 32
#define G5_KC  64
__global__ __launch_bounds__(256) void k_gemm5(const float* __restrict__ XC,
                                               const float* __restrict__ W5f,
                                               const float* __restrict__ W5d,
                                               float* __restrict__ P5,
                                               float* __restrict__ D5) {
    __shared__ __attribute__((aligned(16))) float Wfs[G5_KC][G5_COT+4];
    __shared__ __attribute__((aligned(16))) float Wds[G5_KC][G5_COT+4];
    __shared__ __attribute__((aligned(16))) float Xs[G5_PTT][G5_KC*3+4];
    int co0 = blockIdx.x * G5_COT;
    int p0  = blockIdx.y * G5_PTT;
    int tid = threadIdx.x;
    int tco = tid & 15;                              // 16 groups of 4 co
    int tpt = tid >> 4;                              // 16 groups of 2 pt
    float acc_f[4][2][3] = {};
    float acc_d[4][2][3] = {};
    for (int k0 = 0; k0 < 512; k0 += G5_KC) {
        __syncthreads();
        for (int t = tid; t < G5_COT*G5_KC; t += 256) {
            int c = t >> 6, k = t & 63;              // consecutive t -> consecutive k: coalesced
            Wfs[k][c] = W5f[(size_t)(co0 + c)*512 + k0 + k];
            Wds[k][c] = W5d[(size_t)(co0 + c)*512 + k0 + k];
        }
        for (int t = tid; t < G5_PTT*G5_KC*3; t += 256) {
            int p = t / (G5_KC*3), r = t - p*(G5_KC*3);
            Xs[p][r] = XC[(size_t)(p0 + p)*1536 + k0*3 + r];
        }
        __syncthreads();
        for (int kb = 0; kb < G5_KC; kb += 4) {
            float xq[2][12];
            #pragma unroll
            for (int q = 0; q < 2; ++q) {
                const float4* xp = reinterpret_cast<const float4*>(&Xs[tpt*2+q][kb*3]);
                float4 xa = xp[0], xb = xp[1], xc = xp[2];
                xq[q][0]=xa.x; xq[q][1]=xa.y; xq[q][2]=xa.z; xq[q][3]=xa.w;
                xq[q][4]=xb.x; xq[q][5]=xb.y; xq[q][6]=xb.z; xq[q][7]=xb.w;
                xq[q][8]=xc.x; xq[q][9]=xc.y; xq[q][10]=xc.z; xq[q][11]=xc.w;
            }
            #pragma unroll
            for (int kk = 0; kk < 4; ++kk) {
                int k = kb + kk;
                float4 wf4 = *reinterpret_cast<const float4*>(&Wfs[k][tco*4]);
                float4 wd4 = *reinterpret_cast<const float4*>(&Wds[k][tco*4]);
                float wfv[4] = {wf4.x, wf4.y, wf4.z, wf4.w};
                float wdv[4] = {wd4.x, wd4.y, wd4.z, wd4.w};
                #pragma unroll
                for (int j = 0; j < 4; ++j)
                    #pragma unroll
                    for (int q = 0; q < 2; ++q)
                        #pragma unroll
                        for (int d = 0; d < 3; ++d) {
                            float xe = xq[q][kk*3+d];
                            acc_f[j][q][d] = fmaf(wfv[j], xe, acc_f[j][q][d]);
                            acc_d[j][q][d] = fmaf(wdv[j], xe, acc_d[j][q][d]);
                        }
            }
        }
    }
    #pragma unroll
    for (int q = 0; q < 2; ++q) {
        int pt = p0 + tpt*2 + q;
        #pragma unroll
        for (int j = 0; j < 4; ++j) {
            int co = co0 + tco*4 + j;
            size_t o = ((size_t)pt*1024 + co)*3;
            P5[o]   = acc_f[j][q][0];
            P5[o+1] = acc_f[j][q][1];
            P5[o+2] = acc_f[j][q][2];
            D5[o]   = acc_d[j][q][0];
            D5[o+1] = acc_d[j][q][1];
            D5[o+2] = acc_d[j][q][2];
        }
    }
}

// ---------------- K10: layer-5 pass A ----------------
__global__ __launch_bounds__(256) void k_passA5(const float* __restrict__ P5,
                                                float* __restrict__ part) {
    int p0 = blockIdx.x*16;
    float s[4] = {}, q[4] = {};
    for (int pp = 0; pp < 16; ++pp) {
        size_t base = ((size_t)(p0+pp)*1024)*3;
        #pragma unroll
        for (int qq = 0; qq < 4; ++qq) {
            int co = qq*256 + threadIdx.x;
            size_t o = base + (size_t)co*3;
            float a = P5[o], b = P5[o+1], c = P5[o+2];
            float nn = sqrtf(a*a + b*b + c*c) + 1e-6f;
            s[qq] += nn; q[qq] += nn*nn;
        }
    }
    #pragma unroll
    for (int qq = 0; qq < 4; ++qq) {
        int co = qq*256 + threadIdx.x;
        size_t o = ((size_t)blockIdx.x*1024 + co)*2;
        part[o] = s[qq]; part[o+1] = q[qq];
    }
}

// ---------------- K11: layer-5 pass B (partial mean over n) ----------------
__global__ __launch_bounds__(256) void k_passB5(const float* __restrict__ P5,
                                                const float* __restrict__ D5,
                                                const float* __restrict__ mu,
                                                const float* __restrict__ rstd,
                                                const float* __restrict__ gam,
                                                const float* __restrict__ bet,
                                                float* __restrict__ part) {
    int p0 = blockIdx.x*16;
    float mm[4], rr[4], gg[4], bb[4];
    #pragma unroll
    for (int qq = 0; qq < 4; ++qq) {
        int co = qq*256 + threadIdx.x;
        mm[qq] = mu[co]; rr[qq] = rstd[co]; gg[qq] = gam[co]; bb[qq] = bet[co];
    }
    float acc[4][3] = {};
    for (int pp = 0; pp < 16; ++pp) {
        size_t base = ((size_t)(p0+pp)*1024)*3;
        #pragma unroll
        for (int qq = 0; qq < 4; ++qq) {
            int co = qq*256 + threadIdx.x;
            size_t o = base + (size_t)co*3;
            float a = P5[o], b = P5[o+1], c = P5[o+2];
            float d0 = D5[o], d1 = D5[o+1], d2 = D5[o+2];
            float nn = sqrtf(a*a + b*b + c*c) + 1e-6f;
            float sc = ((nn - mm[qq])*rr[qq]*gg[qq] + bb[qq])/nn;
            float q0 = sc*a, q1 = sc*b, q2 = sc*c;
            float dotv = sc*(a*d0 + b*d1 + c*d2);
            if (dotv < 0.f) {
                float dsq = d0*d0 + d1*d1 + d2*d2;
                float cc  = dotv/(dsq + 1e-6f);
                q0 -= cc*d0; q1 -= cc*d1; q2 -= cc*d2;
            }
            acc[qq][0] += q0; acc[qq][1] += q1; acc[qq][2] += q2;
        }
    }
    #pragma unroll
    for (int qq = 0; qq < 4; ++qq) {
        int co = qq*256 + threadIdx.x;
        size_t o = ((size_t)blockIdx.x*1024 + co)*3;
        part[o] = acc[qq][0]; part[o+1] = acc[qq][1]; part[o+2] = acc[qq][2];
    }
}

// ---------------- K12: final reduce over n-chunks -> d_out ----------------
__global__ __launch_bounds__(256) void k_outred(const float* __restrict__ part,
                                                float* __restrict__ out) {
    int t = blockIdx.x*256 + threadIdx.x;            // over B*1024*3
    if (t >= NB*1024*3) return;
    int d = t % 3; int co = (t/3) % 1024; int b = t/(3*1024);
    float s = 0.f;
    for (int ch = 0; ch < 64; ++ch)
        s += part[((size_t)(b*64 + ch)*1024 + co)*3 + d];
    out[t] = s * (1.f/1024.f);
}

// ---------------- host-side per-layer driver ----------------
template<int CO, int C>
static void run_layer(const float* Xin, int S, const float* Wf, const float* Wd,
                      const float* g, const float* bt, int choff,
                      double* XX, double* DIST, int* IDX,
                      float* Yf, float* Zf, float* Yd, float* Zd,
                      float* PA, float* MU, float* RS, float* XC, hipStream_t stream) {
    constexpr int F = 3*C;
    k_row_sumsq<<<dim3(NROW/4), dim3(256), 0, stream>>>(Xin, S, F, XX);
    size_t dsm = (size_t)2*16*((F < 384 ? F : 384) + 1)*4;   // fp32 staging
    k_dist<<<dim3(NPT/16, NPT/16, NB), dim3(256), dsm, stream>>>(Xin, S, F, XX, DIST);
    k_topk<<<dim3(NROW), dim3(256), 0, stream>>>(DIST, IDX);
    if constexpr (C >= 32) {
        k_yz2<CO, C><<<dim3(CO/32, NROW/32), dim3(256), 0, stream>>>(Xin, S, Wf, Wd, Yf, Zf, Yd, Zd);
    } else {
        k_yz<CO, C><<<dim3(NROW/4), dim3(256), (size_t)4*C*3*4, stream>>>(Xin, S, Wf, Wd, Yf, Zf, Yd, Zd);
    }
    k_passA<CO><<<dim3(NROW/4), dim3(256), 0, stream>>>(Yf, Zf, IDX, PA);
    k_stats2<<<dim3(CO), dim3(256), 0, stream>>>(PA, (NROW/4)*256/CO, CO, (double)((size_t)NROW*KNN), MU, RS);
    k_passB<CO><<<dim3(NROW/4), dim3(256), 0, stream>>>(Yf, Zf, Yd, Zd, IDX, MU, RS, g, bt, XC, choff);
}

extern "C" void kernel_launch(void* const* d_in, const int* in_sizes, int n_in,
                              void* d_out, int out_size, void* d_ws, size_t ws_size,
                              hipStream_t stream) {
    const float* x = (const float*)d_in[0];
    const float* Wf[5]; const float* Wd[5]; const float* G[5]; const float* Bt[5];
    for (int l = 0; l < 5; ++l) {
        Wf[l] = (const float*)d_in[1 + 4*l];
        Wd[l] = (const float*)d_in[2 + 4*l];
        G[l]  = (const float*)d_in[3 + 4*l];
        Bt[l] = (const float*)d_in[4 + 4*l];
    }
    float* ws = (float*)d_ws;
    // workspace layout (float slots)
    size_t oXC  = 0;                                 // 4*1024*512*3 = 6291456
    size_t oX1  = oXC  + (size_t)NROW*512*3;
    size_t oXX  = oX1  + (size_t)NROW*3;             // doubles: NROW*2 slots
    size_t oMU  = oXX  + (size_t)NROW*2;
    size_t oRS  = oMU  + 1024;
    size_t oPA  = oRS  + 1024;                       // 1024*256*2 = 524288
    size_t oPB5 = oPA  + (size_t)256*1024*2;
    size_t oIDX = oPB5 + (size_t)256*1024*3;
    size_t oBIG = oIDX + (size_t)NROW*KNN;
    float*  XC  = ws + oXC;
    float*  X1  = ws + oX1;
    double* XX  = (double*)(ws + oXX);
    float*  MU  = ws + oMU;
    float*  RS  = ws + oRS;
    float*  PA  = ws + oPA;
    float*  PB5 = ws + oPB5;
    int*    IDX = (int*)(ws + oIDX);
    // big region: (dist fp64 + Y/Z) overlapped with (P5 + D5)
    double* DIST = (double*)(ws + oBIG);             // 4194304 doubles = 8388608 slots
    float*  Yf = ws + oBIG + 8388608;
    float*  Zf = Yf + 3145728;
    float*  Yd = Zf + 3145728;
    float*  Zd = Yd + 3145728;
    float*  P5 = ws + oBIG;
    float*  D5 = P5 + (size_t)NROW*1024*3;

    (void)in_sizes; (void)n_in; (void)out_size; (void)ws_size;

    k_transpose_in<<<dim3(48), dim3(256), 0, stream>>>(x, X1);

    // layer 1: C=1 (F=3), CO=64, out channels [0,64)
    run_layer<64, 1>(X1, 3, Wf[0], Wd[0], G[0], Bt[0], 0,
                     XX, DIST, IDX, Yf, Zf, Yd, Zd, PA, MU, RS, XC, stream);
    // layer 2: input = XC[:, :, 0:64], CO=64, out [64,128)
    run_layer<64, 64>(XC + 0*3, 512*3, Wf[1], Wd[1], G[1], Bt[1], 64,
                      XX, DIST, IDX, Yf, Zf, Yd, Zd, PA, MU, RS, XC, stream);
    // layer 3: input = XC[:, :, 64:128], CO=128, out [128,256)
    run_layer<128, 64>(XC + 64*3, 512*3, Wf[2], Wd[2], G[2], Bt[2], 128,
                       XX, DIST, IDX, Yf, Zf, Yd, Zd, PA, MU, RS, XC, stream);
    // layer 4: input = XC[:, :, 128:256], CO=256, out [256,512)
    run_layer<256, 128>(XC + 128*3, 512*3, Wf[3], Wd[3], G[3], Bt[3], 256,
                        XX, DIST, IDX, Yf, Zf, Yd, Zd, PA, MU, RS, XC, stream);

    // layer 5 (tiled GEMM: grid 16 co-tiles x 128 pt-tiles)
    k_gemm5<<<dim3(16, 128), dim3(256), 0, stream>>>(XC, Wf[4], Wd[4], P5, D5);
    k_passA5<<<dim3(NROW/16), dim3(256), 0, stream>>>(P5, PA);
    k_stats2<<<dim3(1024), dim3(256), 0, stream>>>(PA, 256, 1024, (double)NROW, MU, RS);
    k_passB5<<<dim3(NROW/16), dim3(256), 0, stream>>>(P5, D5, MU, RS, G[4], Bt[4], PB5);
    k_outred<<<dim3(48), dim3(256), 0, stream>>>(PB5, (float*)d_out);
}

// Round 16
// 1739.158 us; speedup vs baseline: 2.6932x; 1.0396x over previous
//
#include <hip/hip_runtime.h>
#include <math.h>

#define NB 4
#define NPT 1024
#define KNN 20
#define NROW (NB*NPT)

// ---------------- K1: transpose input (B,3,N) -> (B,N,3) ----------------
__global__ __launch_bounds__(256) void k_transpose_in(const float* __restrict__ x,
                                                      float* __restrict__ X1) {
    int t = blockIdx.x*256 + threadIdx.x;            // over B*N*3
    if (t >= NB*NPT*3) return;
    int d = t % 3; int n = (t/3) % NPT; int b = t/(3*NPT);
    X1[t] = x[(b*3 + d)*NPT + n];
}

// ---------------- K2: per-row sum of squares (fp64) ----------------
__global__ __launch_bounds__(256) void k_row_sumsq(const float* __restrict__ X, int S, int F,
                                                   double* __restrict__ xx) {
    int lane = threadIdx.x & 63;
    int row  = blockIdx.x*4 + (threadIdx.x >> 6);
    const float* p = X + (size_t)row * S;
    double s = 0.0;
    for (int f = lane; f < F; f += 64) { double v = (double)p[f]; s += v*v; }
    for (int off = 32; off; off >>= 1) s += __shfl_down(s, off);
    if (lane == 0) xx[row] = s;
}

// ---------------- K3: tiled distance, fp32 LDS + fp64 accumulate ----------------
__global__ __launch_bounds__(256) void k_dist(const float* __restrict__ X, int S, int F,
                                              const double* __restrict__ xx,
                                              double* __restrict__ dist) {
    extern __shared__ float ds[];
    int b = blockIdx.z, n0 = blockIdx.y*16, m0 = blockIdx.x*16;
    const int CH = 384;
    int Fp = (F < CH ? F : CH) + 1;
    float* Xn = ds;
    float* Xm = ds + 16*Fp;
    double acc = 0.0;
    int mi = threadIdx.x & 15, ni = threadIdx.x >> 4;
    for (int f0 = 0; f0 < F; f0 += CH) {
        int fc = F - f0; if (fc > CH) fc = CH;
        __syncthreads();
        for (int t = threadIdx.x; t < 16*fc; t += 256) {
            int r = t / fc, c = t - r*fc;
            Xn[r*Fp + c] = X[((size_t)(b*NPT + n0 + r))*S + f0 + c];
            Xm[r*Fp + c] = X[((size_t)(b*NPT + m0 + r))*S + f0 + c];
        }
        __syncthreads();
        const float* an = Xn + ni*Fp;
        const float* am = Xm + mi*Fp;
        for (int f = 0; f < fc; ++f)
            acc = fma((double)an[f], (double)am[f], acc);
    }
    dist[((size_t)(b*NPT + n0 + ni))*NPT + (m0 + mi)] = 2.0*acc - xx[b*NPT + m0 + mi];
}

// ---------------- K4: top-20, single wave per row, barrier-free shuffle reduce ----------------
// Lane l owns elements {l + 64q} (q=0..15) in registers. Per round: local scan
// ascending q (strict > keeps lowest index within lane), then 6-step shfl_xor
// butterfly with (value, lower-idx) total-order comparator — wave64 lockstep,
// no __syncthreads. Selection semantics identical: descending value, lowest
// index on ties. IDX output bitwise identical to the block version.
__global__ __launch_bounds__(64) void k_topk(const double* __restrict__ dist,
                                             int* __restrict__ idxo) {
    int row  = blockIdx.x;                           // b*N+n
    int lane = threadIdx.x;                          // 0..63
    const double* dr = dist + (size_t)row * NPT;
    double v[16];
    #pragma unroll
    for (int q = 0; q < 16; ++q) v[q] = dr[lane + 64*q];
    for (int k = 0; k < KNN; ++k) {
        double bv = v[0]; int bq = 0;
        #pragma unroll
        for (int q = 1; q < 16; ++q)
            if (v[q] > bv) { bv = v[q]; bq = q; }    // strict >: lower q (lower idx) wins ties
        int bi = lane + 64*bq;
        #pragma unroll
        for (int off = 32; off; off >>= 1) {
            double ov = __shfl_xor(bv, off);
            int    oi = __shfl_xor(bi, off);
            if (ov > bv || (ov == bv && oi < bi)) { bv = ov; bi = oi; }
        }
        if (lane == 0) idxo[row*KNN + k] = bi;       // all lanes hold the same (bv,bi)
        if ((bi & 63) == lane) v[bi >> 6] = -1.0e300;
    }
}

// ---------------- K5a: Y/Z precompute, layer-1 only (C=1, W is L1-resident) ----------------
template<int CO, int C>
__global__ __launch_bounds__(256) void k_yz(const float* __restrict__ X, int S,
                                            const float* __restrict__ Wf,
                                            const float* __restrict__ Wd,
                                            float* __restrict__ Yf, float* __restrict__ Zf,
                                            float* __restrict__ Yd, float* __restrict__ Zd) {
    extern __shared__ float xl[];                    // [4][C*3]
    constexpr int REP = 256/CO;
    constexpr int PPG = 4/REP;                       // points per thread
    int p0 = blockIdx.x * 4;
    for (int t = threadIdx.x; t < 4*C*3; t += 256) {
        int pt = t / (C*3); int r = t - pt*(C*3);
        xl[t] = X[((size_t)(p0 + pt))*S + r];
    }
    __syncthreads();
    int co  = threadIdx.x % CO;
    int sub = threadIdx.x / CO;
    float yf[PPG][3] = {}, zf[PPG][3] = {}, yd[PPG][3] = {}, zd[PPG][3] = {};
    const float* wfr = Wf + (size_t)co*2*C;
    const float* wdr = Wd + (size_t)co*2*C;
    for (int i = 0; i < C; ++i) {
        float wfa = wfr[i], wfb = wfr[C+i];
        float wda = wdr[i], wdb = wdr[C+i];
        float wfz = wfb - wfa, wdz = wdb - wda;
        #pragma unroll
        for (int q = 0; q < PPG; ++q) {
            int pt = sub*PPG + q;
            const float* xv = xl + pt*(C*3) + i*3;
            #pragma unroll
            for (int d3 = 0; d3 < 3; ++d3) {
                float xe = xv[d3];
                yf[q][d3] = fmaf(wfa, xe, yf[q][d3]);
                zf[q][d3] = fmaf(wfz, xe, zf[q][d3]);
                yd[q][d3] = fmaf(wda, xe, yd[q][d3]);
                zd[q][d3] = fmaf(wdz, xe, zd[q][d3]);
            }
        }
    }
    #pragma unroll
    for (int q = 0; q < PPG; ++q) {
        int pt = sub*PPG + q;
        size_t o = ((size_t)(p0+pt)*CO + co)*3;
        #pragma unroll
        for (int d3 = 0; d3 < 3; ++d3) {
            Yf[o+d3] = yf[q][d3]; Zf[o+d3] = zf[q][d3];
            Yd[o+d3] = yd[q][d3]; Zd[o+d3] = zd[q][d3];
        }
    }
}

// ---------------- K5b: Y/Z precompute, GEMM-style LDS tiling (layers 2-4) ----------------
template<int CO, int C>
__global__ __launch_bounds__(256) void k_yz2(const float* __restrict__ X, int S,
                                             const float* __restrict__ Wf,
                                             const float* __restrict__ Wd,
                                             float* __restrict__ Yf, float* __restrict__ Zf,
                                             float* __restrict__ Yd, float* __restrict__ Zd) {
    __shared__ float Waf[32][33], Wbf[32][33], Wad[32][33], Wbd[32][33];
    __shared__ float Xs[32][97];                     // 32 pt x 96 (=32i*3) +1 pad
    int co0 = blockIdx.x * 32;
    int p0  = blockIdx.y * 32;
    int tid = threadIdx.x;
    int tco = tid & 15;                              // thread owns co0+tco, co0+tco+16
    int tpt = tid >> 4;                              // thread owns 2 pts
    float yf[2][2][3] = {}, zf[2][2][3] = {}, yd[2][2][3] = {}, zd[2][2][3] = {};
    for (int i0 = 0; i0 < C; i0 += 32) {
        __syncthreads();
        for (int t = tid; t < 1024; t += 256) {
            int c = t >> 5, i = t & 31;
            const float* wfr = Wf + (size_t)(co0 + c)*2*C + i0 + i;
            const float* wdr = Wd + (size_t)(co0 + c)*2*C + i0 + i;
            Waf[c][i] = wfr[0];
            Wbf[c][i] = wfr[C];
            Wad[c][i] = wdr[0];
            Wbd[c][i] = wdr[C];
        }
        for (int t = tid; t < 32*96; t += 256) {
            int p = t / 96, r = t - p*96;
            Xs[p][r] = X[(size_t)(p0 + p)*S + i0*3 + r];
        }
        __syncthreads();
        for (int k = 0; k < 32; ++k) {
            float waf[2], wzf[2], wad[2], wzd[2];
            #pragma unroll
            for (int j = 0; j < 2; ++j) {
                int c = tco + 16*j;
                waf[j] = Waf[c][k];
                wzf[j] = Wbf[c][k] - waf[j];
                wad[j] = Wad[c][k];
                wzd[j] = Wbd[c][k] - wad[j];
            }
            float xv[2][3];
            #pragma unroll
            for (int q = 0; q < 2; ++q)
                #pragma unroll
                for (int d = 0; d < 3; ++d)
                    xv[q][d] = Xs[tpt*2+q][k*3+d];
            #pragma unroll
            for (int j = 0; j < 2; ++j)
                #pragma unroll
                for (int q = 0; q < 2; ++q)
                    #pragma unroll
                    for (int d = 0; d < 3; ++d) {
                        float xe = xv[q][d];
                        yf[j][q][d] = fmaf(waf[j], xe, yf[j][q][d]);
                        zf[j][q][d] = fmaf(wzf[j], xe, zf[j][q][d]);
                        yd[j][q][d] = fmaf(wad[j], xe, yd[j][q][d]);
                        zd[j][q][d] = fmaf(wzd[j], xe, zd[j][q][d]);
                    }
        }
    }
    #pragma unroll
    for (int q = 0; q < 2; ++q) {
        int pt = p0 + tpt*2 + q;
        #pragma unroll
        for (int j = 0; j < 2; ++j) {
            int co = co0 + tco + 16*j;
            size_t o = ((size_t)pt*CO + co)*3;
            #pragma unroll
            for (int d = 0; d < 3; ++d) {
                Yf[o+d] = yf[j][q][d];
                Zf[o+d] = zf[j][q][d];
                Yd[o+d] = yd[j][q][d];
                Zd[o+d] = zd[j][q][d];
            }
        }
    }
}

// ---------------- K6: pass A — 4 rows/block (grid 1024) ----------------
template<int CO>
__global__ __launch_bounds__(256) void k_passA(const float* __restrict__ Yf,
                                               const float* __restrict__ Zf,
                                               const int* __restrict__ idx,
                                               float* __restrict__ part) {
    constexpr int PNG = CO/64;                       // rows per sub-thread; (256/CO)*PNG = 4
    int co  = threadIdx.x % CO;
    int sub = threadIdx.x / CO;
    int p0  = blockIdx.x*4 + sub*PNG;
    float s = 0.f, q = 0.f;
    for (int pp = 0; pp < PNG; ++pp) {
        int row = p0 + pp;
        int b   = row >> 10;
        size_t zo = ((size_t)row*CO + co)*3;
        float z0 = Zf[zo], z1 = Zf[zo+1], z2 = Zf[zo+2];
        const int* ir = idx + row*KNN;
        #pragma unroll 4
        for (int k = 0; k < KNN; ++k) {
            int j = ir[k];
            size_t yo = ((size_t)((b<<10) + j)*CO + co)*3;
            float a0 = Yf[yo] + z0, a1 = Yf[yo+1] + z1, a2 = Yf[yo+2] + z2;
            float nn = sqrtf(a0*a0 + a1*a1 + a2*a2) + 1e-6f;
            s += nn; q += nn*nn;
        }
    }
    size_t o = ((size_t)blockIdx.x*256 + threadIdx.x)*2;
    part[o] = s; part[o+1] = q;
}

// ---------------- K7: stats finalize, parallel (one block per channel, fp64 tree) ----------------
__global__ __launch_bounds__(256) void k_stats2(const float* __restrict__ part, int nchunk, int CO,
                                                double cnt, float* __restrict__ mu,
                                                float* __restrict__ rstd) {
    __shared__ double sv[4], qv[4];
    int c = blockIdx.x;                              // channel
    double s = 0.0, q = 0.0;
    for (int ch = threadIdx.x; ch < nchunk; ch += 256) {
        size_t o = ((size_t)ch*CO + c)*2;
        s += (double)part[o]; q += (double)part[o+1];
    }
    #pragma unroll
    for (int off = 32; off; off >>= 1) {
        s += __shfl_down(s, off);
        q += __shfl_down(q, off);
    }
    int w = threadIdx.x >> 6;
    if ((threadIdx.x & 63) == 0) { sv[w] = s; qv[w] = q; }
    __syncthreads();
    if (threadIdx.x == 0) {
        double S = sv[0] + sv[1] + sv[2] + sv[3];
        double Q = qv[0] + qv[1] + qv[2] + qv[3];
        double m = S/cnt;
        double v = Q/cnt - m*m;
        mu[c]   = (float)m;
        rstd[c] = (float)(1.0/sqrt(v + 1e-5));
    }
}

// ---------------- K8: pass B — 4 rows/block (grid 1024) ----------------
template<int CO>
__global__ __launch_bounds__(256) void k_passB(const float* __restrict__ Yf,
                                               const float* __restrict__ Zf,
                                               const float* __restrict__ Yd,
                                               const float* __restrict__ Zd,
                                               const int* __restrict__ idx,
                                               const float* __restrict__ mu,
                                               const float* __restrict__ rstd,
                                               const float* __restrict__ gam,
                                               const float* __restrict__ bet,
                                               float* __restrict__ XC, int choff) {
    constexpr int PNG = CO/64;                       // rows per sub-thread; (256/CO)*PNG = 4
    int co  = threadIdx.x % CO;
    int sub = threadIdx.x / CO;
    int p0  = blockIdx.x*4 + sub*PNG;
    float m = mu[co], rs = rstd[co], g = gam[co], bt = bet[co];
    for (int pp = 0; pp < PNG; ++pp) {
        int row = p0 + pp;
        int b   = row >> 10;
        size_t zo = ((size_t)row*CO + co)*3;
        float zf0 = Zf[zo], zf1 = Zf[zo+1], zf2 = Zf[zo+2];
        float zd0 = Zd[zo], zd1 = Zd[zo+1], zd2 = Zd[zo+2];
        const int* ir = idx + row*KNN;
        float a0 = 0.f, a1 = 0.f, a2 = 0.f;
        #pragma unroll 4
        for (int k = 0; k < KNN; ++k) {
            int j = ir[k];
            size_t yo = ((size_t)((b<<10) + j)*CO + co)*3;
            float pv0 = Yf[yo] + zf0, pv1 = Yf[yo+1] + zf1, pv2 = Yf[yo+2] + zf2;
            float d0  = Yd[yo] + zd0, d1  = Yd[yo+1] + zd1, d2  = Yd[yo+2] + zd2;
            float nn  = sqrtf(pv0*pv0 + pv1*pv1 + pv2*pv2) + 1e-6f;
            float nbn = (nn - m)*rs*g + bt;
            float sc  = nbn / nn;
            float q0 = sc*pv0, q1 = sc*pv1, q2 = sc*pv2;
            float dotv = sc*(pv0*d0 + pv1*d1 + pv2*d2);
            if (dotv < 0.f) {
                float dsq = d0*d0 + d1*d1 + d2*d2;
                float cc  = dotv/(dsq + 1e-6f);
                q0 -= cc*d0; q1 -= cc*d1; q2 -= cc*d2;
            }
            a0 += q0; a1 += q1; a2 += q2;
        }
        size_t oo = ((size_t)row*512 + choff + co)*3;
        XC[oo]   = a0*(1.f/KNN);
        XC[oo+1] = a1*(1.f/KNN);
        XC[oo+2] = a2*(1.f/KNN);
    }
}

// ---------------- K9: layer-5 GEMM, K-chunk 32 (LDS 30.2KB -> ~5 blocks/CU) ----------------
// FMA order per output unchanged (k ascending through all 512, same j/q/d
// order) -> bitwise identical to the K64 version.
#define G5_COT 64
#define G5_PTT 32
#define G5_KC  32
__global__ __launch_bounds__(256) void k_gemm5(const float* __restrict__ XC,
                                               const float* __restrict__ W5f,
                                               const float* __restrict__ W5d,
                                               float* __restrict__ P5,
                                               float* __restrict__ D5) {
    __shared__ __attribute__((aligned(16))) float Wfs[G5_KC][G5_COT+4];
    __shared__ __attribute__((aligned(16))) float Wds[G5_KC][G5_COT+4];
    __shared__ __attribute__((aligned(16))) float Xs[G5_PTT][G5_KC*3+4];
    int co0 = blockIdx.x * G5_COT;
    int p0  = blockIdx.y * G5_PTT;
    int tid = threadIdx.x;
    int tco = tid & 15;                              // 16 groups of 4 co
    int tpt = tid >> 4;                              // 16 groups of 2 pt
    float acc_f[4][2][3] = {};
    float acc_d[4][2][3] = {};
    for (int k0 = 0; k0 < 512; k0 += G5_KC) {
        __syncthreads();
        for (int t = tid; t < G5_COT*G5_KC; t += 256) {
            int c = t >> 5, k = t & 31;              // consecutive t -> consecutive k: coalesced
            Wfs[k][c] = W5f[(size_t)(co0 + c)*512 + k0 + k];
            Wds[k][c] = W5d[(size_t)(co0 + c)*512 + k0 + k];
        }
        for (int t = tid; t < G5_PTT*G5_KC*3; t += 256) {
            int p = t / (G5_KC*3), r = t - p*(G5_KC*3);
            Xs[p][r] = XC[(size_t)(p0 + p)*1536 + k0*3 + r];
        }
        __syncthreads();
        for (int kb = 0; kb < G5_KC; kb += 4) {
            float xq[2][12];
            #pragma unroll
            for (int q = 0; q < 2; ++q) {
                const float4* xp = reinterpret_cast<const float4*>(&Xs[tpt*2+q][kb*3]);
                float4 xa = xp[0], xb = xp[1], xc = xp[2];
                xq[q][0]=xa.x; xq[q][1]=xa.y; xq[q][2]=xa.z; xq[q][3]=xa.w;
                xq[q][4]=xb.x; xq[q][5]=xb.y; xq[q][6]=xb.z; xq[q][7]=xb.w;
                xq[q][8]=xc.x; xq[q][9]=xc.y; xq[q][10]=xc.z; xq[q][11]=xc.w;
            }
            #pragma unroll
            for (int kk = 0; kk < 4; ++kk) {
                int k = kb + kk;
                float4 wf4 = *reinterpret_cast<const float4*>(&Wfs[k][tco*4]);
                float4 wd4 = *reinterpret_cast<const float4*>(&Wds[k][tco*4]);
                float wfv[4] = {wf4.x, wf4.y, wf4.z, wf4.w};
                float wdv[4] = {wd4.x, wd4.y, wd4.z, wd4.w};
                #pragma unroll
                for (int j = 0; j < 4; ++j)
                    #pragma unroll
                    for (int q = 0; q < 2; ++q)
                        #pragma unroll
                        for (int d = 0; d < 3; ++d) {
                            float xe = xq[q][kk*3+d];
                            acc_f[j][q][d] = fmaf(wfv[j], xe, acc_f[j][q][d]);
                            acc_d[j][q][d] = fmaf(wdv[j], xe, acc_d[j][q][d]);
                        }
            }
        }
    }
    #pragma unroll
    for (int q = 0; q < 2; ++q) {
        int pt = p0 + tpt*2 + q;
        #pragma unroll
        for (int j = 0; j < 4; ++j) {
            int co = co0 + tco*4 + j;
            size_t o = ((size_t)pt*1024 + co)*3;
            P5[o]   = acc_f[j][q][0];
            P5[o+1] = acc_f[j][q][1];
            P5[o+2] = acc_f[j][q][2];
            D5[o]   = acc_d[j][q][0];
            D5[o+1] = acc_d[j][q][1];
            D5[o+2] = acc_d[j][q][2];
        }
    }
}

// ---------------- K10: layer-5 pass A ----------------
__global__ __launch_bounds__(256) void k_passA5(const float* __restrict__ P5,
                                                float* __restrict__ part) {
    int p0 = blockIdx.x*16;
    float s[4] = {}, q[4] = {};
    for (int pp = 0; pp < 16; ++pp) {
        size_t base = ((size_t)(p0+pp)*1024)*3;
        #pragma unroll
        for (int qq = 0; qq < 4; ++qq) {
            int co = qq*256 + threadIdx.x;
            size_t o = base + (size_t)co*3;
            float a = P5[o], b = P5[o+1], c = P5[o+2];
            float nn = sqrtf(a*a + b*b + c*c) + 1e-6f;
            s[qq] += nn; q[qq] += nn*nn;
        }
    }
    #pragma unroll
    for (int qq = 0; qq < 4; ++qq) {
        int co = qq*256 + threadIdx.x;
        size_t o = ((size_t)blockIdx.x*1024 + co)*2;
        part[o] = s[qq]; part[o+1] = q[qq];
    }
}

// ---------------- K11: layer-5 pass B (partial mean over n) ----------------
__global__ __launch_bounds__(256) void k_passB5(const float* __restrict__ P5,
                                                const float* __restrict__ D5,
                                                const float* __restrict__ mu,
                                                const float* __restrict__ rstd,
                                                const float* __restrict__ gam,
                                                const float* __restrict__ bet,
                                                float* __restrict__ part) {
    int p0 = blockIdx.x*16;
    float mm[4], rr[4], gg[4], bb[4];
    #pragma unroll
    for (int qq = 0; qq < 4; ++qq) {
        int co = qq*256 + threadIdx.x;
        mm[qq] = mu[co]; rr[qq] = rstd[co]; gg[qq] = gam[co]; bb[qq] = bet[co];
    }
    float acc[4][3] = {};
    for (int pp = 0; pp < 16; ++pp) {
        size_t base = ((size_t)(p0+pp)*1024)*3;
        #pragma unroll
        for (int qq = 0; qq < 4; ++qq) {
            int co = qq*256 + threadIdx.x;
            size_t o = base + (size_t)co*3;
            float a = P5[o], b = P5[o+1], c = P5[o+2];
            float d0 = D5[o], d1 = D5[o+1], d2 = D5[o+2];
            float nn = sqrtf(a*a + b*b + c*c) + 1e-6f;
            float sc = ((nn - mm[qq])*rr[qq]*gg[qq] + bb[qq])/nn;
            float q0 = sc*a, q1 = sc*b, q2 = sc*c;
            float dotv = sc*(a*d0 + b*d1 + c*d2);
            if (dotv < 0.f) {
                float dsq = d0*d0 + d1*d1 + d2*d2;
                float cc  = dotv/(dsq + 1e-6f);
                q0 -= cc*d0; q1 -= cc*d1; q2 -= cc*d2;
            }
            acc[qq][0] += q0; acc[qq][1] += q1; acc[qq][2] += q2;
        }
    }
    #pragma unroll
    for (int qq = 0; qq < 4; ++qq) {
        int co = qq*256 + threadIdx.x;
        size_t o = ((size_t)blockIdx.x*1024 + co)*3;
        part[o] = acc[qq][0]; part[o+1] = acc[qq][1]; part[o+2] = acc[qq][2];
    }
}

// ---------------- K12: final reduce over n-chunks -> d_out ----------------
__global__ __launch_bounds__(256) void k_outred(const float* __restrict__ part,
                                                float* __restrict__ out) {
    int t = blockIdx.x*256 + threadIdx.x;            // over B*1024*3
    if (t >= NB*1024*3) return;
    int d = t % 3; int co = (t/3) % 1024; int b = t/(3*1024);
    float s = 0.f;
    for (int ch = 0; ch < 64; ++ch)
        s += part[((size_t)(b*64 + ch)*1024 + co)*3 + d];
    out[t] = s * (1.f/1024.f);
}

// ---------------- host-side per-layer driver ----------------
template<int CO, int C>
static void run_layer(const float* Xin, int S, const float* Wf, const float* Wd,
                      const float* g, const float* bt, int choff,
                      double* XX, double* DIST, int* IDX,
                      float* Yf, float* Zf, float* Yd, float* Zd,
                      float* PA, float* MU, float* RS, float* XC, hipStream_t stream) {
    constexpr int F = 3*C;
    k_row_sumsq<<<dim3(NROW/4), dim3(256), 0, stream>>>(Xin, S, F, XX);
    size_t dsm = (size_t)2*16*((F < 384 ? F : 384) + 1)*4;   // fp32 staging
    k_dist<<<dim3(NPT/16, NPT/16, NB), dim3(256), dsm, stream>>>(Xin, S, F, XX, DIST);
    k_topk<<<dim3(NROW), dim3(64), 0, stream>>>(DIST, IDX);
    if constexpr (C >= 32) {
        k_yz2<CO, C><<<dim3(CO/32, NROW/32), dim3(256), 0, stream>>>(Xin, S, Wf, Wd, Yf, Zf, Yd, Zd);
    } else {
        k_yz<CO, C><<<dim3(NROW/4), dim3(256), (size_t)4*C*3*4, stream>>>(Xin, S, Wf, Wd, Yf, Zf, Yd, Zd);
    }
    k_passA<CO><<<dim3(NROW/4), dim3(256), 0, stream>>>(Yf, Zf, IDX, PA);
    k_stats2<<<dim3(CO), dim3(256), 0, stream>>>(PA, (NROW/4)*256/CO, CO, (double)((size_t)NROW*KNN), MU, RS);
    k_passB<CO><<<dim3(NROW/4), dim3(256), 0, stream>>>(Yf, Zf, Yd, Zd, IDX, MU, RS, g, bt, XC, choff);
}

extern "C" void kernel_launch(void* const* d_in, const int* in_sizes, int n_in,
                              void* d_out, int out_size, void* d_ws, size_t ws_size,
                              hipStream_t stream) {
    const float* x = (const float*)d_in[0];
    const float* Wf[5]; const float* Wd[5]; const float* G[5]; const float* Bt[5];
    for (int l = 0; l < 5; ++l) {
        Wf[l] = (const float*)d_in[1 + 4*l];
        Wd[l] = (const float*)d_in[2 + 4*l];
        G[l]  = (const float*)d_in[3 + 4*l];
        Bt[l] = (const float*)d_in[4 + 4*l];
    }
    float* ws = (float*)d_ws;
    // workspace layout (float slots)
    size_t oXC  = 0;                                 // 4*1024*512*3 = 6291456
    size_t oX1  = oXC  + (size_t)NROW*512*3;
    size_t oXX  = oX1  + (size_t)NROW*3;             // doubles: NROW*2 slots
    size_t oMU  = oXX  + (size_t)NROW*2;
    size_t oRS  = oMU  + 1024;
    size_t oPA  = oRS  + 1024;                       // 1024*256*2 = 524288
    size_t oPB5 = oPA  + (size_t)256*1024*2;
    size_t oIDX = oPB5 + (size_t)256*1024*3;
    size_t oBIG = oIDX + (size_t)NROW*KNN;
    float*  XC  = ws + oXC;
    float*  X1  = ws + oX1;
    double* XX  = (double*)(ws + oXX);
    float*  MU  = ws + oMU;
    float*  RS  = ws + oRS;
    float*  PA  = ws + oPA;
    float*  PB5 = ws + oPB5;
    int*    IDX = (int*)(ws + oIDX);
    // big region: (dist fp64 + Y/Z) overlapped with (P5 + D5)
    double* DIST = (double*)(ws + oBIG);             // 4194304 doubles = 8388608 slots
    float*  Yf = ws + oBIG + 8388608;
    float*  Zf = Yf + 3145728;
    float*  Yd = Zf + 3145728;
    float*  Zd = Yd + 3145728;
    float*  P5 = ws + oBIG;
    float*  D5 = P5 + (size_t)NROW*1024*3;

    (void)in_sizes; (void)n_in; (void)out_size; (void)ws_size;

    k_transpose_in<<<dim3(48), dim3(256), 0, stream>>>(x, X1);

    // layer 1: C=1 (F=3), CO=64, out channels [0,64)
    run_layer<64, 1>(X1, 3, Wf[0], Wd[0], G[0], Bt[0], 0,
                     XX, DIST, IDX, Yf, Zf, Yd, Zd, PA, MU, RS, XC, stream);
    // layer 2: input = XC[:, :, 0:64], CO=64, out [64,128)
    run_layer<64, 64>(XC + 0*3, 512*3, Wf[1], Wd[1], G[1], Bt[1], 64,
                      XX, DIST, IDX, Yf, Zf, Yd, Zd, PA, MU, RS, XC, stream);
    // layer 3: input = XC[:, :, 64:128], CO=128, out [128,256)
    run_layer<128, 64>(XC + 64*3, 512*3, Wf[2], Wd[2], G[2], Bt[2], 128,
                       XX, DIST, IDX, Yf, Zf, Yd, Zd, PA, MU, RS, XC, stream);
    // layer 4: input = XC[:, :, 128:256], CO=256, out [256,512)
    run_layer<256, 128>(XC + 128*3, 512*3, Wf[3], Wd[3], G[3], Bt[3], 256,
                        XX, DIST, IDX, Yf, Zf, Yd, Zd, PA, MU, RS, XC, stream);

    // layer 5 (tiled GEMM: grid 16 co-tiles x 128 pt-tiles)
    k_gemm5<<<dim3(16, 128), dim3(256), 0, stream>>>(XC, Wf[4], Wd[4], P5, D5);
    k_passA5<<<dim3(NROW/16), dim3(256), 0, stream>>>(P5, PA);
    k_stats2<<<dim3(1024), dim3(256), 0, stream>>>(PA, 256, 1024, (double)NROW, MU, RS);
    k_passB5<<<dim3(NROW/16), dim3(256), 0, stream>>>(P5, D5, MU, RS, G[4], Bt[4], PB5);
    k_outred<<<dim3(48), dim3(256), 0, stream>>>(PB5, (float*)d_out);
}